// Round 6
// baseline (112.424 us; speedup 1.0000x reference)
//
#include <hip/hip_runtime.h>
#include <hip/hip_bf16.h>

// QConv1d: x (8,64,16384) f32, w (64,64,9) f32, bias (64) f32
// out (8,64,16384) f32 = conv1d(x, w, pad=4) * 0.125 + bias
// Strategy: cast to bf16 (weights pre-scaled by 0.125 — exact, power of two),
// MFMA f32_16x16x32_bf16, fp32 accumulate, fp32 out.
// Round-6: LTILE 256->128 (1024 blocks = ~3-4 blocks/CU instead of exactly 2)
// so staging of one block overlaps the MFMA K-loop of its CU-mates; the
// block itself is a serial stage->barrier->MFMA pipeline with no intra-block
// latency hiding. Costs +6% halo fetch (~0.3 us) for +50% co-residency.
#define C_IN    64
#define L_IN    16384
#define O_OUT   64
#define KTAP    9
#define LTILE   128
#define ROWS    144      // LTILE + 16 halo rows (global l in [l0-8, l0+136))
#define RSTRIDE 72       // 64 + 8 pad (multiple of 8 -> 16B-aligned b128 rows)

typedef short          bf16x8 __attribute__((ext_vector_type(8)));   // MFMA A/B frag
typedef unsigned short u16x8  __attribute__((ext_vector_type(8)));
typedef unsigned int   u32x4  __attribute__((ext_vector_type(4)));
typedef float          f32x4  __attribute__((ext_vector_type(4)));   // MFMA C/D frag
typedef float          f32x8v __attribute__((ext_vector_type(8)));

static __device__ __forceinline__ unsigned short f2bf(float f) {
  __hip_bfloat16 h = __float2bfloat16(f);   // round-to-nearest
  return __builtin_bit_cast(unsigned short, h);
}

// pack two floats -> one u32 of two bf16 (lo in low 16 bits)
static __device__ __forceinline__ unsigned int pk2(float lo, float hi) {
  return (unsigned int)f2bf(lo) | ((unsigned int)f2bf(hi) << 16);
}

// ---------------------------------------------------------------------------
// Pre-kernel: w[o][c][t] fp32 (stride-9 taps) -> W2[t][o][c] bf16 (c contig),
// pre-scaled by 0.125 (exact: power-of-two only touches the exponent).
// ---------------------------------------------------------------------------
__global__ void w_rearrange(const float* __restrict__ w,
                            unsigned short* __restrict__ w2) {
    int i = blockIdx.x * 256 + threadIdx.x;       // i = t*4096 + o*64 + c
    if (i >= KTAP * O_OUT * C_IN) return;
    int t  = i >> 12;
    int oc = i & 4095;                            // o*64 + c
    w2[i] = f2bf(w[oc * KTAP + t] * 0.125f);
}

// ---------------------------------------------------------------------------
// Main kernel: one block = one n, one 128-wide L tile, all 64 outputs.
// 4 waves in a 2(O) x 2(L) grid; each wave owns 32 O x 64 L.
// ---------------------------------------------------------------------------
__global__ __launch_bounds__(256) void qconv_kernel(
    const float* __restrict__ x,
    const unsigned short* __restrict__ w2,    // bf16 bits, pre-scaled
    const float* __restrict__ bias,
    float* __restrict__ out) {

  __shared__ __align__(16) unsigned short xs[ROWS][RSTRIDE];  // bf16 x tile, [l][c]

  const int tid = threadIdx.x;
  const int n   = blockIdx.x >> 7;
  const int l0  = (blockIdx.x & 127) << 7;     // tile base along L
  const float* xn = x + (size_t)n * C_IN * L_IN;

  // ---- Phase 1: stage x tile into LDS, fp32->bf16, transposed to [l][c] --
  // 144 8x8 transpose units (tid < 144 active); pair-packed bf16 conversion.
  for (int idx = tid; idx < ROWS; idx += 256) {
    const int cb = idx & 7;
    const int lb = idx >> 3;
    const int c0 = cb << 3;
    const int gl0 = l0 - 8 + (lb << 3);        // global l of first row (32B-aligned)
    if (gl0 >= 0 && gl0 + 8 <= L_IN) {
      f32x8v v[8];
#pragma unroll
      for (int i = 0; i < 8; ++i)
        v[i] = *reinterpret_cast<const f32x8v*>(xn + (size_t)(c0 + i) * L_IN + gl0);
#pragma unroll
      for (int j = 0; j < 8; ++j) {
        u32x4 wv;
#pragma unroll
        for (int p = 0; p < 4; ++p)
          wv[p] = pk2(v[2 * p][j], v[2 * p + 1][j]);
        *reinterpret_cast<u32x4*>(&xs[(lb << 3) + j][c0]) = wv;
      }
    } else {
      // edge tiles only: element-wise zero-fill outside [0, L)
      unsigned short vb[8][8];                  // [i=c][j=l]
      for (int i = 0; i < 8; ++i)
        for (int j = 0; j < 8; ++j) {
          int gl = gl0 + j;
          vb[i][j] = (gl >= 0 && gl < L_IN)
                         ? f2bf(xn[(size_t)(c0 + i) * L_IN + gl])
                         : (unsigned short)0;
        }
      for (int j = 0; j < 8; ++j) {
        u16x8 wv;
        for (int i = 0; i < 8; ++i) wv[i] = vb[i][j];
        *reinterpret_cast<u16x8*>(&xs[(lb << 3) + j][c0]) = wv;
      }
    }
  }
  __syncthreads();

  // ---- Phase 2: MFMA main loop ------------------------------------------
  const int wave = tid >> 6;
  const int lane = tid & 63;
  const int wr   = wave >> 1;       // O half: o in [32*wr, 32*wr+32)
  const int wc   = wave & 1;        // L half: l-offset wc*64
  const int col  = lane & 15;
  const int quad = lane >> 4;

  f32x4 acc[2][4];
#pragma unroll
  for (int m = 0; m < 2; ++m)
#pragma unroll
    for (int lt = 0; lt < 4; ++lt) acc[m][lt] = (f32x4){0.f, 0.f, 0.f, 0.f};

  // LDS row for out-col l = l0 + wc*64 + lt*16 + col at tap t:
  //   r = (l + t - 4) - (l0 - 8) = wc*64 + lt*16 + col + t + 4
  const int rbase = (wc << 6) + col + 4;

  for (int t = 0; t < KTAP; ++t) {
    // A-frags: W2[t][o][c]; lane holds o = o0+col, c = k*32 + quad*8 .. +7
    bf16x8 a[2][2];
#pragma unroll
    for (int m = 0; m < 2; ++m)
#pragma unroll
      for (int k = 0; k < 2; ++k)
        a[m][k] = *reinterpret_cast<const bf16x8*>(
            w2 + (t << 12) + (((wr << 5) + (m << 4) + col) << 6) + (k << 5) + (quad << 3));

#pragma unroll
    for (int k = 0; k < 2; ++k) {
#pragma unroll
      for (int lt = 0; lt < 4; ++lt) {
        const int r = rbase + t + (lt << 4);
        const bf16x8 b = *reinterpret_cast<const bf16x8*>(&xs[r][(k << 5) + (quad << 3)]);
        acc[0][lt] = __builtin_amdgcn_mfma_f32_16x16x32_bf16(a[0][k], b, acc[0][lt], 0, 0, 0);
        acc[1][lt] = __builtin_amdgcn_mfma_f32_16x16x32_bf16(a[1][k], b, acc[1][lt], 0, 0, 0);
      }
    }
  }

  // ---- Phase 3: epilogue: + bias (0.125 folded into w), fp32 store ------
  // D layout: col = lane&15 -> l, row = quad*4 + reg -> o
#pragma unroll
  for (int m = 0; m < 2; ++m) {
    const int obase = (wr << 5) + (m << 4) + (quad << 2);
    float bv[4];
#pragma unroll
    for (int reg = 0; reg < 4; ++reg) bv[reg] = bias[obase + reg];
#pragma unroll
    for (int lt = 0; lt < 4; ++lt) {
      const int l = l0 + (wc << 6) + (lt << 4) + col;
#pragma unroll
      for (int reg = 0; reg < 4; ++reg) {
        const int o = obase + reg;
        out[((size_t)(n * O_OUT + o) << 14) + l] = acc[m][lt][reg] + bv[reg];
      }
    }
  }
}

extern "C" void kernel_launch(void* const* d_in, const int* in_sizes, int n_in,
                              void* d_out, int out_size, void* d_ws, size_t ws_size,
                              hipStream_t stream) {
  const float*    x    = (const float*)d_in[0];
  const float*    w    = (const float*)d_in[1];
  const float*    bias = (const float*)d_in[2];
  float*          out  = (float*)d_out;
  unsigned short* w2   = (unsigned short*)d_ws;   // 73728 B scratch (bf16 weights)

  // 1) rearrange + downcast + pre-scale weights into d_ws (runs every call)
  w_rearrange<<<(KTAP * O_OUT * C_IN + 255) / 256, 256, 0, stream>>>(w, w2);

  // 2) fused conv-as-GEMM: 8 n * 128 L-tiles = 1024 blocks
  qconv_kernel<<<8 * (L_IN / LTILE), 256, 0, stream>>>(x, w2, bias, out);
}

// Round 7
// 103.272 us; speedup vs baseline: 1.0886x; 1.0886x over previous
//
#include <hip/hip_runtime.h>
#include <hip/hip_bf16.h>

// QConv1d: x (8,64,16384) f32, w (64,64,9) f32, bias (64) f32
// out (8,64,16384) f32 = conv1d(x, w, pad=4) * 0.125 + bias
// Round-7: latency-hiding restructure (round-6 rocprof: MfmaUtil 7%, VALU 5%,
// hbm 17% -- pure latency serialization). LTILE=256, 512 blocks (2/CU):
//  - half-tile staging pipeline: stage rows[0,144), barrier, ISSUE loads for
//    rows[144,272), compute K-half0 while they fly, ds_write mid-K0, barrier,
//    K-half1. Staging HBM latency hides behind K0.
//  - weight frags double-buffered over t (a_cur/a_nxt) so no vmcnt(0) drain
//    per tap inside the K-loop (round-6 VGPR=68 shows nothing was resident).
//  - epilogue per half; weights pre-scaled by exact 0.125; bf16 MFMA.
#define C_IN    64
#define L_IN    16384
#define O_OUT   64
#define KTAP    9
#define LTILE   256
#define ROWS    272      // l in [l0-8, l0+264)
#define ROWS_A  144      // first-stage rows [0,144); K0 uses rows [4,140)
#define RSTRIDE 72       // 64 + 8 pad (multiple of 8 -> 16B-aligned b128 rows)

typedef short          bf16x8 __attribute__((ext_vector_type(8)));   // MFMA A/B frag
typedef unsigned int   u32x4  __attribute__((ext_vector_type(4)));
typedef float          f32x4  __attribute__((ext_vector_type(4)));   // MFMA C/D frag
typedef float          f32x8v __attribute__((ext_vector_type(8)));

static __device__ __forceinline__ unsigned short f2bf(float f) {
  __hip_bfloat16 h = __float2bfloat16(f);   // round-to-nearest
  return __builtin_bit_cast(unsigned short, h);
}
static __device__ __forceinline__ unsigned int pk2(float lo, float hi) {
  return (unsigned int)f2bf(lo) | ((unsigned int)f2bf(hi) << 16);
}

// ---------------------------------------------------------------------------
// Pre-kernel: w[o][c][t] fp32 -> W2[t][o][c] bf16 (c contig), pre-scaled 0.125.
// ---------------------------------------------------------------------------
__global__ void w_rearrange(const float* __restrict__ w,
                            unsigned short* __restrict__ w2) {
    int i = blockIdx.x * 256 + threadIdx.x;       // i = t*4096 + o*64 + c
    if (i >= KTAP * O_OUT * C_IN) return;
    int t  = i >> 12;
    int oc = i & 4095;                            // o*64 + c
    w2[i] = f2bf(w[oc * KTAP + t] * 0.125f);
}

// 8x8 unit: load 8 c-rows x 8 l fp32 (edge-guarded)
static __device__ __forceinline__ void load_unit(const float* __restrict__ xn,
                                                 int l0, int lb, int cb,
                                                 f32x8v v[8]) {
  const int c0  = cb << 3;
  const int gl0 = l0 - 8 + (lb << 3);
  if (gl0 >= 0 && gl0 + 8 <= L_IN) {
#pragma unroll
    for (int i = 0; i < 8; ++i)
      v[i] = *reinterpret_cast<const f32x8v*>(xn + (size_t)(c0 + i) * L_IN + gl0);
  } else {
    for (int i = 0; i < 8; ++i)
      for (int j = 0; j < 8; ++j) {
        int gl = gl0 + j;
        v[i][j] = (gl >= 0 && gl < L_IN) ? xn[(size_t)(c0 + i) * L_IN + gl] : 0.f;
      }
  }
}
// transpose + cvt + 8x ds_write_b128 into rows [lb*8, lb*8+8)
static __device__ __forceinline__ void write_unit(unsigned short xs[ROWS][RSTRIDE],
                                                  int lb, int cb, const f32x8v v[8]) {
  const int c0 = cb << 3;
#pragma unroll
  for (int j = 0; j < 8; ++j) {
    u32x4 wv;
#pragma unroll
    for (int p = 0; p < 4; ++p) wv[p] = pk2(v[2 * p][j], v[2 * p + 1][j]);
    *reinterpret_cast<u32x4*>(&xs[(lb << 3) + j][c0]) = wv;
  }
}

// ---------------------------------------------------------------------------
// Main kernel: one block = one n, one 256-wide L tile, all 64 outputs.
// 4 waves: wr = O-half (32 o), wc = L-quarter within each 128-col half.
// ---------------------------------------------------------------------------
__global__ __launch_bounds__(256) void qconv_kernel(
    const float* __restrict__ x,
    const unsigned short* __restrict__ w2,    // bf16 bits, pre-scaled
    const float* __restrict__ bias,
    float* __restrict__ out) {

  __shared__ __align__(16) unsigned short xs[ROWS][RSTRIDE];  // bf16 x tile [l][c]

  const int tid = threadIdx.x;
  const int n   = blockIdx.x >> 6;
  const int l0  = (blockIdx.x & 63) << 8;
  const float* xn = x + (size_t)n * C_IN * L_IN;

  const int wave = tid >> 6;
  const int lane = tid & 63;
  const int wr   = wave >> 1;       // O half
  const int wc   = wave & 1;        // 64-col quarter within current 128 half
  const int col  = lane & 15;
  const int quad = lane >> 4;

  // ---- stage A: rows [0,144) = 144 units, threads 0..143 ----------------
  if (tid < ROWS_A) {
    f32x8v va[8];
    load_unit(xn, l0, tid >> 3, tid & 7, va);
    write_unit(xs, tid >> 3, tid & 7, va);
  }
  __syncthreads();

  // bias (L2-resident)
  float bv[2][4];
#pragma unroll
  for (int m = 0; m < 2; ++m)
#pragma unroll
    for (int reg = 0; reg < 4; ++reg)
      bv[m][reg] = bias[(wr << 5) + (m << 4) + (quad << 2) + reg];

  // weight frag loader: W2[t][o][c], o = wr*32+m*16+col, c = k*32+quad*8
  const unsigned short* wbase = w2 + ((((wr << 5) + col) << 6) + (quad << 3));
  auto lda = [&](bf16x8 a[2][2], int t) {
#pragma unroll
    for (int m = 0; m < 2; ++m)
#pragma unroll
      for (int k = 0; k < 2; ++k)
        a[m][k] = *reinterpret_cast<const bf16x8*>(wbase + (t << 12) + (m << 10) + (k << 5));
  };

  auto kstep = [&](int h, int t, const bf16x8 a[2][2], f32x4 acc[2][4]) {
    const int rb = (h << 7) + (wc << 6) + col + 4 + t;
#pragma unroll
    for (int k = 0; k < 2; ++k)
#pragma unroll
      for (int lt = 0; lt < 4; ++lt) {
        const bf16x8 b =
            *reinterpret_cast<const bf16x8*>(&xs[rb + (lt << 4)][(k << 5) + (quad << 3)]);
        acc[0][lt] = __builtin_amdgcn_mfma_f32_16x16x32_bf16(a[0][k], b, acc[0][lt], 0, 0, 0);
        acc[1][lt] = __builtin_amdgcn_mfma_f32_16x16x32_bf16(a[1][k], b, acc[1][lt], 0, 0, 0);
      }
  };

  auto epi = [&](int h, const f32x4 acc[2][4]) {
#pragma unroll
    for (int m = 0; m < 2; ++m) {
      const int obase = (wr << 5) + (m << 4) + (quad << 2);
#pragma unroll
      for (int lt = 0; lt < 4; ++lt) {
        const int l = l0 + (h << 7) + (wc << 6) + (lt << 4) + col;
#pragma unroll
        for (int reg = 0; reg < 4; ++reg)
          out[((size_t)(n * O_OUT + obase + reg) << 14) + l] = acc[m][lt][reg] + bv[m][reg];
      }
    }
  };

  // ---- K-half0 with stage-B pipelined underneath -------------------------
  bf16x8 ac[2][2], an[2][2];
  lda(ac, 0);
  lda(an, 1);

  // issue stage-B loads (rows [144,272) = 128 units, threads 0..127) AFTER
  // the first two taps' weight loads so early MFMA waits don't drain them.
  const bool actB = tid < 128;
  f32x8v vbuf[8];
  if (actB) load_unit(xn, l0, 18 + (tid >> 3), tid & 7, vbuf);

  f32x4 acc[2][4];
#pragma unroll
  for (int m = 0; m < 2; ++m)
#pragma unroll
    for (int lt = 0; lt < 4; ++lt) acc[m][lt] = (f32x4){0.f, 0.f, 0.f, 0.f};

#pragma unroll
  for (int t = 0; t < KTAP; ++t) {
    kstep(0, t, ac, acc);
#pragma unroll
    for (int m = 0; m < 2; ++m)
#pragma unroll
      for (int k = 0; k < 2; ++k) ac[m][k] = an[m][k];
    if (t + 2 < KTAP) lda(an, t + 2);
    if (t == 1 && actB)   // ~2 taps in: loads have had K-time to land
      write_unit(xs, 18 + (tid >> 3), tid & 7, vbuf);
  }
  epi(0, acc);
  __syncthreads();

  // ---- K-half1 ------------------------------------------------------------
  lda(ac, 0);
  lda(an, 1);
#pragma unroll
  for (int m = 0; m < 2; ++m)
#pragma unroll
    for (int lt = 0; lt < 4; ++lt) acc[m][lt] = (f32x4){0.f, 0.f, 0.f, 0.f};

#pragma unroll
  for (int t = 0; t < KTAP; ++t) {
    kstep(1, t, ac, acc);
#pragma unroll
    for (int m = 0; m < 2; ++m)
#pragma unroll
      for (int k = 0; k < 2; ++k) ac[m][k] = an[m][k];
    if (t + 2 < KTAP) lda(an, t + 2);
  }
  epi(1, acc);
}

extern "C" void kernel_launch(void* const* d_in, const int* in_sizes, int n_in,
                              void* d_out, int out_size, void* d_ws, size_t ws_size,
                              hipStream_t stream) {
  const float*    x    = (const float*)d_in[0];
  const float*    w    = (const float*)d_in[1];
  const float*    bias = (const float*)d_in[2];
  float*          out  = (float*)d_out;
  unsigned short* w2   = (unsigned short*)d_ws;   // 73728 B scratch (bf16 weights)

  w_rearrange<<<(KTAP * O_OUT * C_IN + 255) / 256, 256, 0, stream>>>(w, w2);
  qconv_kernel<<<8 * (L_IN / LTILE), 256, 0, stream>>>(x, w2, bias, out);
}